// Round 8
// baseline (373.984 us; speedup 1.0000x reference)
//
#include <hip/hip_runtime.h>
#include <hip/hip_fp16.h>
#include <cstdint>

// Problem constants (match reference)
constexpr int N_NODES = 100000;
constexpr int E_EDGES = 1600000;
constexpr float NEG_SLOPE = 0.2f;
constexpr float INV_TEMP = 1.0f / 0.7f;
constexpr int NCHUNK = (N_NODES + 1023) / 1024;   // 98 scan chunks of 1024

constexpr int PLACE_B = 4;
constexpr int PLACE_T = E_EDGES / PLACE_B;   // 400000 (exact)
constexpr int HIST_B = 8;
constexpr int HIST_T = E_EDGES / HIST_B;     // 200000 (exact)
constexpr int MLP_B = 2;
constexpr int MLP_T = E_EDGES / MLP_B;       // 800000 (exact)

__device__ __forceinline__ __half2 bits_to_h2(int bits) {
    return *reinterpret_cast<__half2*>(&bits);
}

// packed relu: t>0 ? t : 0   (__hmax2 not in ROCm 7.2 headers; __hgt2 gives
// packed 1.0/0.0 mask)
__device__ __forceinline__ __half2 h2_relu(__half2 a) {
    const __half2 z = __floats2half2_rn(0.f, 0.f);
    return __hmul2(a, __hgt2(a, z));
}

// ---------------------------------------------------------------------------
// K1: per-node transform. xp2[n][c] = half2(head0_c, head1_c)  (interleaved);
//     a_src/a_dst attention dots [N,2] fp32.
// ---------------------------------------------------------------------------
__global__ void k_node(const float* __restrict__ x, const float* __restrict__ W,
                       const float* __restrict__ att_src, const float* __restrict__ att_dst,
                       __half2* __restrict__ xp2, float* __restrict__ a_src,
                       float* __restrict__ a_dst) {
    int n = blockIdx.x * blockDim.x + threadIdx.x;
    if (n >= N_NODES) return;
    float xi[16];
    const float4* xv = (const float4*)(x + (size_t)n * 16);
    ((float4*)xi)[0] = xv[0];
    ((float4*)xi)[1] = xv[1];
    ((float4*)xi)[2] = xv[2];
    ((float4*)xi)[3] = xv[3];
    float as0 = 0.f, as1 = 0.f, ad0 = 0.f, ad1 = 0.f;
    __half2 hbuf[32];
#pragma unroll
    for (int c = 0; c < 32; c++) {
        float acc0 = 0.f, acc1 = 0.f;
#pragma unroll
        for (int k = 0; k < 16; k++) {
            acc0 += xi[k] * W[k * 64 + c];
            acc1 += xi[k] * W[k * 64 + 32 + c];
        }
        hbuf[c] = __floats2half2_rn(acc0, acc1);
        as0 += acc0 * att_src[c];
        as1 += acc1 * att_src[32 + c];
        ad0 += acc0 * att_dst[c];
        ad1 += acc1 * att_dst[32 + c];
    }
    float4* dst4 = (float4*)(xp2 + (size_t)n * 32);   // 128 B contiguous
#pragma unroll
    for (int q = 0; q < 8; q++) dst4[q] = ((float4*)hbuf)[q];
    ((float2*)a_src)[n] = make_float2(as0, as1);
    ((float2*)a_dst)[n] = make_float2(ad0, ad1);
}

// ---------------------------------------------------------------------------
// K2: zero ints (counts + cursor)
// ---------------------------------------------------------------------------
__global__ void k_zero_i(int* __restrict__ p, int count) {
    int i = blockIdx.x * blockDim.x + threadIdx.x;
    if (i < count) p[i] = 0;
}

// ---------------------------------------------------------------------------
// K3: histogram of dst, 8 edges/thread in coalesced stride-T phases
//     (8 independent atomic chains in flight per thread)
// ---------------------------------------------------------------------------
__global__ void k_hist(const int* __restrict__ dst, int* __restrict__ counts) {
    int t = blockIdx.x * blockDim.x + threadIdx.x;
    if (t >= HIST_T) return;
    int d[HIST_B];
#pragma unroll
    for (int k = 0; k < HIST_B; k++) d[k] = dst[t + k * HIST_T];
#pragma unroll
    for (int k = 0; k < HIST_B; k++) atomicAdd(&counts[d[k]], 1);
}

// ---------------------------------------------------------------------------
// K4a/b: exclusive prefix scan of counts -> offs (chunk-local) + chunk bases.
//        k_scan2 also packs w2 (32 floats) into half2[16] for k_mlp.
// ---------------------------------------------------------------------------
__global__ void k_scan1(const int* __restrict__ counts, int* __restrict__ offs,
                        int* __restrict__ partials) {
    __shared__ int sd[256];
    int t = threadIdx.x;
    int base = blockIdx.x * 1024 + t * 4;
    int c0 = (base + 0 < N_NODES) ? counts[base + 0] : 0;
    int c1 = (base + 1 < N_NODES) ? counts[base + 1] : 0;
    int c2 = (base + 2 < N_NODES) ? counts[base + 2] : 0;
    int c3 = (base + 3 < N_NODES) ? counts[base + 3] : 0;
    int s1 = c0 + c1, s2 = s1 + c2, s3 = s2 + c3;
    sd[t] = s3;
    __syncthreads();
    for (int off = 1; off < 256; off <<= 1) {
        int v = (t >= off) ? sd[t - off] : 0;
        __syncthreads();
        sd[t] += v;
        __syncthreads();
    }
    int excl = (t > 0) ? sd[t - 1] : 0;
    if (t == 255) partials[blockIdx.x] = sd[255];
    if (base + 0 < N_NODES) offs[base + 0] = excl;
    if (base + 1 < N_NODES) offs[base + 1] = excl + c0;
    if (base + 2 < N_NODES) offs[base + 2] = excl + s1;
    if (base + 3 < N_NODES) offs[base + 3] = excl + s2;
}

__global__ void k_scan2(int* __restrict__ partials, const float* __restrict__ w2,
                        __half2* __restrict__ w2h) {
    __shared__ int sd[128];
    int t = threadIdx.x;
    int v = (t < NCHUNK) ? partials[t] : 0;
    sd[t] = v;
    __syncthreads();
    for (int off = 1; off < 128; off <<= 1) {
        int w = (t >= off) ? sd[t - off] : 0;
        __syncthreads();
        sd[t] += w;
        __syncthreads();
    }
    if (t < NCHUNK) partials[t] = (t > 0) ? sd[t - 1] : 0;
    if (t < 16) w2h[t] = __floats2half2_rn(w2[2 * t], w2[2 * t + 1]);
}

// ---------------------------------------------------------------------------
// K5: CSR placement + attention weights, 4 edges/thread in coalesced
//     stride-T phases. Each phase (edge loads / a-gathers / exp / atomics /
//     record writes) is batched so 4 chains run concurrently.
//     Record is 8 B: {s, half2(w0,w1)}.
// ---------------------------------------------------------------------------
__global__ void k_place(const int* __restrict__ src, const int* __restrict__ dst,
                        const int* __restrict__ offs, const int* __restrict__ partials,
                        const float* __restrict__ a_src, const float* __restrict__ a_dst,
                        int* __restrict__ cursor, int2* __restrict__ recs) {
    int t = blockIdx.x * blockDim.x + threadIdx.x;
    if (t >= PLACE_T) return;
    int s[PLACE_B], d[PLACE_B];
#pragma unroll
    for (int k = 0; k < PLACE_B; k++) {
        int e = t + k * PLACE_T;
        s[k] = src[e];
        d[k] = dst[e];
    }
    float2 As[PLACE_B], Ad[PLACE_B];
#pragma unroll
    for (int k = 0; k < PLACE_B; k++) As[k] = ((const float2*)a_src)[s[k]];
#pragma unroll
    for (int k = 0; k < PLACE_B; k++) Ad[k] = ((const float2*)a_dst)[d[k]];
    int wb[PLACE_B];
#pragma unroll
    for (int k = 0; k < PLACE_B; k++) {
        float e0 = As[k].x + Ad[k].x; e0 = (e0 > 0.f) ? e0 : NEG_SLOPE * e0;
        float e1 = As[k].y + Ad[k].y; e1 = (e1 > 0.f) ? e1 : NEG_SLOPE * e1;
        __half2 hw = __floats2half2_rn(__expf(e0), __expf(e1));
        wb[k] = *reinterpret_cast<int*>(&hw);
    }
    int pos[PLACE_B];
#pragma unroll
    for (int k = 0; k < PLACE_B; k++)
        pos[k] = offs[d[k]] + partials[d[k] >> 10] + atomicAdd(&cursor[d[k]], 1);
#pragma unroll
    for (int k = 0; k < PLACE_B; k++)
        recs[pos[k]] = make_int2(s[k], wb[k]);
}

// ---------------------------------------------------------------------------
// K6: one 32-lane HALF-WAVE per dst node (2 nodes/wave). Lane c handles both
//     heads of channel c via packed-half2 math. fp16 block-accumulate U=8
//     edges, flush to fp32. Records are tight 8 B {s,wbits} (seq read).
//     Softmax division deferred; fused MLP factorization epilogue.
// ---------------------------------------------------------------------------
__global__ void k_agg(const int2* __restrict__ recs, const int* __restrict__ offs,
                      const int* __restrict__ partials, const int* __restrict__ deg,
                      const float* __restrict__ a_src, const float* __restrict__ a_dst,
                      const __half2* __restrict__ xp2, const float* __restrict__ bias,
                      const float* __restrict__ w1, const float* __restrict__ b1,
                      __half* __restrict__ u, __half* __restrict__ v) {
    int hw = (blockIdx.x * blockDim.x + threadIdx.x) >> 5;   // half-wave id = node
    int ch = threadIdx.x & 31;
    if (hw >= N_NODES) return;
    int d = hw;

    // self-loop term (fp32, once per node)
    float2 Ad  = ((const float2*)a_dst)[d];
    float2 As0 = ((const float2*)a_src)[d];
    float e0 = As0.x + Ad.x; e0 = (e0 > 0.f) ? e0 : NEG_SLOPE * e0;
    float e1 = As0.y + Ad.y; e1 = (e1 > 0.f) ? e1 : NEG_SLOPE * e1;
    float w00 = __expf(e0), w01 = __expf(e1);
    float2 xself = __half22float2(xp2[d * 32 + ch]);
    float num0 = w00 * xself.x, num1 = w01 * xself.y;
    float den0 = w00, den1 = w01;

    int base = offs[d] + partials[d >> 10];
    int cnt = deg[d];
    int last = (cnt > 0) ? (cnt - 1) : 0;

    constexpr int U = 8;
    int rounds = (cnt + U - 1) / U;
    for (int r = 0; r < rounds; r++) {
        int j = r * U;
        int2 rc[U];
#pragma unroll
        for (int k = 0; k < U; k++) {
            int jj = j + k;
            int cidx = (jj < cnt) ? jj : last;
            rc[k] = recs[base + cidx];
        }
        __half2 xv[U];
#pragma unroll
        for (int k = 0; k < U; k++)
            xv[k] = xp2[rc[k].x * 32 + ch];
        __half2 nblk = __floats2half2_rn(0.f, 0.f);
        __half2 dblk = nblk;
#pragma unroll
        for (int k = 0; k < U; k++) {
            int wb = (j + k < cnt) ? rc[k].y : 0;   // masks clamped tail dups
            __half2 w = bits_to_h2(wb);
            dblk = __hadd2(dblk, w);
            nblk = __hfma2(w, xv[k], nblk);
        }
        float2 nf = __half22float2(nblk);
        float2 df = __half22float2(dblk);
        num0 += nf.x; num1 += nf.y;
        den0 += df.x; den1 += df.y;
    }

    // head mean + bias: lane c holds full h[c] (both heads local)
    float h = 0.5f * (num0 / (den0 + 1e-16f) + num1 / (den1 + 1e-16f)) + bias[ch];

    // fused MLP factorization: width-32 shfl broadcast within the half-wave
    float uu = b1[ch], vv = 0.f;
#pragma unroll
    for (int c = 0; c < 32; c++) {
        float hc = __shfl(h, c, 32);
        uu += hc * w1[c * 32 + ch];
        vv += hc * w1[(32 + c) * 32 + ch];
    }
    u[d * 32 + ch] = __float2half(uu);
    v[d * 32 + ch] = __float2half(vv);
}

// ---------------------------------------------------------------------------
// K7: per-edge logits in ORIGINAL edge order (coalesced out writes, no
//     write amplification), 2 edges/thread. u/v fp16 rows gathered (L3-
//     resident); packed-half2 dot, final combine fp32.
// ---------------------------------------------------------------------------
__global__ void k_mlp(const int* __restrict__ src, const int* __restrict__ dst,
                      const __half2* __restrict__ u2, const __half2* __restrict__ v2,
                      const __half2* __restrict__ w2h, const float* __restrict__ b2,
                      float* __restrict__ out) {
    int t = blockIdx.x * blockDim.x + threadIdx.x;
    if (t >= MLP_T) return;
    __half2 wl[16];
#pragma unroll
    for (int q = 0; q < 4; q++) ((float4*)wl)[q] = ((const float4*)w2h)[q];
    int s[MLP_B], d[MLP_B];
#pragma unroll
    for (int k = 0; k < MLP_B; k++) {
        s[k] = src[t + k * MLP_T];
        d[k] = dst[t + k * MLP_T];
    }
    float4 ua[MLP_B][4], va[MLP_B][4];
#pragma unroll
    for (int k = 0; k < MLP_B; k++) {
        const float4* up4 = (const float4*)(u2 + s[k] * 16);
        const float4* vp4 = (const float4*)(v2 + d[k] * 16);
#pragma unroll
        for (int q = 0; q < 4; q++) { ua[k][q] = up4[q]; va[k][q] = vp4[q]; }
    }
#pragma unroll
    for (int k = 0; k < MLP_B; k++) {
        const __half2* uh = (const __half2*)ua[k];
        const __half2* vh = (const __half2*)va[k];
        const __half2 z2 = __floats2half2_rn(0.f, 0.f);
        __half2 acc0 = z2, acc1 = z2, acc2 = z2, acc3 = z2;
#pragma unroll
        for (int q = 0; q < 16; q += 4) {
            acc0 = __hfma2(h2_relu(__hadd2(uh[q + 0], vh[q + 0])), wl[q + 0], acc0);
            acc1 = __hfma2(h2_relu(__hadd2(uh[q + 1], vh[q + 1])), wl[q + 1], acc1);
            acc2 = __hfma2(h2_relu(__hadd2(uh[q + 2], vh[q + 2])), wl[q + 2], acc2);
            acc3 = __hfma2(h2_relu(__hadd2(uh[q + 3], vh[q + 3])), wl[q + 3], acc3);
        }
        float2 f0 = __half22float2(acc0);
        float2 f1 = __half22float2(acc1);
        float2 f2 = __half22float2(acc2);
        float2 f3 = __half22float2(acc3);
        float acc = b2[0] + (f0.x + f0.y) + (f1.x + f1.y) + (f2.x + f2.y) + (f3.x + f3.y);
        out[t + k * MLP_T] = acc * INV_TEMP;
    }
}

// ---------------------------------------------------------------------------
extern "C" void kernel_launch(void* const* d_in, const int* in_sizes, int n_in,
                              void* d_out, int out_size, void* d_ws, size_t ws_size,
                              hipStream_t stream) {
    const float* x       = (const float*)d_in[0];
    const int*   eidx    = (const int*)d_in[1];          // [2,E] int32
    const float* W       = (const float*)d_in[2];
    const float* att_src = (const float*)d_in[3];
    const float* att_dst = (const float*)d_in[4];
    const float* bias    = (const float*)d_in[5];
    const float* w1      = (const float*)d_in[6];
    const float* b1      = (const float*)d_in[7];
    const float* w2      = (const float*)d_in[8];
    const float* b2      = (const float*)d_in[9];
    float* out = (float*)d_out;

    const int* src = eidx;             // row 0
    const int* dst = eidx + E_EDGES;   // row 1

    // Workspace layout (~41 MB total; 16B alignment holds at each boundary).
    int* counts   = (int*)d_ws;                      // N
    int* cursor   = counts + N_NODES;                // N  (== deg after k_place)
    int* offs     = cursor + N_NODES;                // N
    int* partials = offs + N_NODES;                  // 128
    __half2* w2h  = (__half2*)(partials + 128);      // 16 half2 (64 B)
    int2* recs    = (int2*)(w2h + 16);               // E 8-B records (12.8 MB)
    float* a_src  = (float*)(recs + E_EDGES);        // 2N
    float* a_dst  = a_src + 2 * N_NODES;             // 2N
    __half2* xp2  = (__half2*)(a_dst + 2 * N_NODES); // 32N half2 (12.8 MB)
    __half* u     = (__half*)(xp2 + 32 * (size_t)N_NODES);  // 32N halves (6.4 MB)
    __half* v     = u + 32 * (size_t)N_NODES;               // 32N halves (6.4 MB)

    constexpr int BS = 256;

    // K1: node transform
    k_node<<<(N_NODES + BS - 1) / BS, BS, 0, stream>>>(x, W, att_src, att_dst, xp2, a_src, a_dst);

    // K2: zero counts + cursor (contiguous 2N ints)
    k_zero_i<<<(2 * N_NODES + BS - 1) / BS, BS, 0, stream>>>(counts, 2 * N_NODES);

    // K3: degree histogram (8 edges/thread)
    k_hist<<<(HIST_T + BS - 1) / BS, BS, 0, stream>>>(dst, counts);

    // K4: exclusive scan counts -> offs (chunk-local) + chunk bases; pack w2
    k_scan1<<<NCHUNK, 256, 0, stream>>>(counts, offs, partials);
    k_scan2<<<1, 128, 0, stream>>>(partials, w2, w2h);

    // K5: CSR placement + attention weights (4 edges/thread)
    k_place<<<(PLACE_T + BS - 1) / BS, BS, 0, stream>>>(src, dst, offs, partials,
                                                       a_src, a_dst, cursor, recs);

    // K6: half-wave-per-node aggregation + fused MLP factorization
    {
        long long threads = (long long)N_NODES * 32;
        int grid = (int)((threads + BS - 1) / BS);
        k_agg<<<grid, BS, 0, stream>>>(recs, offs, partials, cursor, a_src, a_dst,
                                       xp2, bias, w1, b1, u, v);
    }

    // K7: per-edge logits (edge order, 2 edges/thread)
    k_mlp<<<(MLP_T + BS - 1) / BS, BS, 0, stream>>>(src, dst, (const __half2*)u,
                                                   (const __half2*)v, w2h, b2, out);
}

// Round 9
// 373.461 us; speedup vs baseline: 1.0014x; 1.0014x over previous
//
#include <hip/hip_runtime.h>
#include <hip/hip_fp16.h>
#include <cstdint>

// Problem constants (match reference)
constexpr int N_NODES = 100000;
constexpr int E_EDGES = 1600000;
constexpr float NEG_SLOPE = 0.2f;
constexpr float INV_TEMP = 1.0f / 0.7f;
constexpr int NCHUNK = (N_NODES + 1023) / 1024;   // 98 scan chunks of 1024

// XCD partitioning: blockIdx%8 ~ XCD (locality heuristic only; correctness
// does not depend on the mapping). 100000/8 = 12500 nodes per partition.
constexpr int NPART = 8;
constexpr int PART_N = N_NODES / NPART;   // 12500

constexpr int HIST_K = 128;    // blocks per partition in k_hist
constexpr int PLACE_K = 128;   // blocks per partition in k_place
constexpr int AGG_K = 200;     // blocks per partition in k_agg
constexpr int MLP_B = 2;
constexpr int MLP_T = E_EDGES / MLP_B;   // 800000 (exact)

__device__ __forceinline__ __half2 bits_to_h2(int bits) {
    return *reinterpret_cast<__half2*>(&bits);
}

// packed relu (no __hmax2 in ROCm 7.2 headers; __hgt2 gives packed 1/0 mask)
__device__ __forceinline__ __half2 h2_relu(__half2 a) {
    const __half2 z = __floats2half2_rn(0.f, 0.f);
    return __hmul2(a, __hgt2(a, z));
}

// global CSR offset of node d (chunk-local offs + chunk base); d==N -> E
__device__ __forceinline__ int goff(const int* __restrict__ offs,
                                    const int* __restrict__ partials, int d) {
    return (d >= N_NODES) ? E_EDGES : (offs[d] + partials[d >> 10]);
}

// ---------------------------------------------------------------------------
// K1: per-node transform. xp2[n][c] = half2(head0_c, head1_c)  (interleaved);
//     a_src/a_dst attention dots [N,2] fp32. Also zeroes counts[n] (fused).
// ---------------------------------------------------------------------------
__global__ void k_node(const float* __restrict__ x, const float* __restrict__ W,
                       const float* __restrict__ att_src, const float* __restrict__ att_dst,
                       __half2* __restrict__ xp2, float* __restrict__ a_src,
                       float* __restrict__ a_dst, int* __restrict__ counts) {
    int n = blockIdx.x * blockDim.x + threadIdx.x;
    if (n >= N_NODES) return;
    counts[n] = 0;
    float xi[16];
    const float4* xv = (const float4*)(x + (size_t)n * 16);
    ((float4*)xi)[0] = xv[0];
    ((float4*)xi)[1] = xv[1];
    ((float4*)xi)[2] = xv[2];
    ((float4*)xi)[3] = xv[3];
    float as0 = 0.f, as1 = 0.f, ad0 = 0.f, ad1 = 0.f;
    __half2 hbuf[32];
#pragma unroll
    for (int c = 0; c < 32; c++) {
        float acc0 = 0.f, acc1 = 0.f;
#pragma unroll
        for (int k = 0; k < 16; k++) {
            acc0 += xi[k] * W[k * 64 + c];
            acc1 += xi[k] * W[k * 64 + 32 + c];
        }
        hbuf[c] = __floats2half2_rn(acc0, acc1);
        as0 += acc0 * att_src[c];
        as1 += acc1 * att_src[32 + c];
        ad0 += acc0 * att_dst[c];
        ad1 += acc1 * att_dst[32 + c];
    }
    float4* dst4 = (float4*)(xp2 + (size_t)n * 32);   // 128 B contiguous
#pragma unroll
    for (int q = 0; q < 8; q++) dst4[q] = ((float4*)hbuf)[q];
    ((float2*)a_src)[n] = make_float2(as0, as1);
    ((float2*)a_dst)[n] = make_float2(ad0, ad1);
}

// ---------------------------------------------------------------------------
// K2: degree histogram, XCD-partitioned: block b handles only dst in
//     partition (b&7); counts-slice atomics stay in one XCD's L2.
// ---------------------------------------------------------------------------
__global__ void k_hist(const int* __restrict__ dst, int* __restrict__ counts) {
    int part = blockIdx.x & 7;
    int rank = blockIdx.x >> 3;
    int lo = part * PART_N, hi = lo + PART_N;
    for (int e = rank * 256 + threadIdx.x; e < E_EDGES; e += HIST_K * 256) {
        int d = dst[e];
        if (d >= lo && d < hi) atomicAdd(&counts[d], 1);
    }
}

// ---------------------------------------------------------------------------
// K3a/b: exclusive prefix scan of counts -> offs (chunk-local) + chunk bases.
//        k_scan2 also packs w2 (32 floats) into half2[16] for k_mlp.
// ---------------------------------------------------------------------------
__global__ void k_scan1(const int* __restrict__ counts, int* __restrict__ offs,
                        int* __restrict__ partials) {
    __shared__ int sd[256];
    int t = threadIdx.x;
    int base = blockIdx.x * 1024 + t * 4;
    int c0 = (base + 0 < N_NODES) ? counts[base + 0] : 0;
    int c1 = (base + 1 < N_NODES) ? counts[base + 1] : 0;
    int c2 = (base + 2 < N_NODES) ? counts[base + 2] : 0;
    int c3 = (base + 3 < N_NODES) ? counts[base + 3] : 0;
    int s1 = c0 + c1, s2 = s1 + c2, s3 = s2 + c3;
    sd[t] = s3;
    __syncthreads();
    for (int off = 1; off < 256; off <<= 1) {
        int v = (t >= off) ? sd[t - off] : 0;
        __syncthreads();
        sd[t] += v;
        __syncthreads();
    }
    int excl = (t > 0) ? sd[t - 1] : 0;
    if (t == 255) partials[blockIdx.x] = sd[255];
    if (base + 0 < N_NODES) offs[base + 0] = excl;
    if (base + 1 < N_NODES) offs[base + 1] = excl + c0;
    if (base + 2 < N_NODES) offs[base + 2] = excl + s1;
    if (base + 3 < N_NODES) offs[base + 3] = excl + s2;
}

__global__ void k_scan2(int* __restrict__ partials, const float* __restrict__ w2,
                        __half2* __restrict__ w2h) {
    __shared__ int sd[128];
    int t = threadIdx.x;
    int v = (t < NCHUNK) ? partials[t] : 0;
    sd[t] = v;
    __syncthreads();
    for (int off = 1; off < 128; off <<= 1) {
        int w = (t >= off) ? sd[t - off] : 0;
        __syncthreads();
        sd[t] += w;
        __syncthreads();
    }
    if (t < NCHUNK) partials[t] = (t > 0) ? sd[t - 1] : 0;
    if (t < 16) w2h[t] = __floats2half2_rn(w2[2 * t], w2[2 * t + 1]);
}

// ---------------------------------------------------------------------------
// K4: CSR placement + attention weights, XCD-partitioned. Block b writes only
//     records of partition (b&7): a contiguous ~1.6 MB CSR region that fits
//     in one XCD's L2 -> lines written back once, no cross-XCD ping-pong.
//     Cursor-free: pos = goff(d) + atomicSub(counts[d],1) - 1.
//     Record is 8 B: {s, half2(w0,w1)}.
// ---------------------------------------------------------------------------
__global__ void k_place(const int* __restrict__ src, const int* __restrict__ dst,
                        const int* __restrict__ offs, const int* __restrict__ partials,
                        const float* __restrict__ a_src, const float* __restrict__ a_dst,
                        int* __restrict__ counts, int2* __restrict__ recs) {
    int part = blockIdx.x & 7;
    int rank = blockIdx.x >> 3;
    int lo = part * PART_N, hi = lo + PART_N;
    for (int e = rank * 256 + threadIdx.x; e < E_EDGES; e += PLACE_K * 256) {
        int d = dst[e];
        if (d >= lo && d < hi) {
            int s = src[e];
            float2 As = ((const float2*)a_src)[s];
            float2 Ad = ((const float2*)a_dst)[d];
            float e0 = As.x + Ad.x; e0 = (e0 > 0.f) ? e0 : NEG_SLOPE * e0;
            float e1 = As.y + Ad.y; e1 = (e1 > 0.f) ? e1 : NEG_SLOPE * e1;
            __half2 hw = __floats2half2_rn(__expf(e0), __expf(e1));
            int wb = *reinterpret_cast<int*>(&hw);
            int pos = goff(offs, partials, d) + atomicSub(&counts[d], 1) - 1;
            recs[pos] = make_int2(s, wb);
        }
    }
}

// ---------------------------------------------------------------------------
// K5: aggregation, XCD-partitioned by node range (reads its partition's recs
//     from the L2 that just wrote them). One 32-lane half-wave per node;
//     packed-half2 math; fp16 block-accumulate U=8 edges, fp32 flush.
//     deg recomputed from goff diffs (no counts dependency).
//     Fused per-node MLP factorization epilogue.
// ---------------------------------------------------------------------------
__global__ void k_agg(const int2* __restrict__ recs, const int* __restrict__ offs,
                      const int* __restrict__ partials, const float* __restrict__ a_src,
                      const float* __restrict__ a_dst, const __half2* __restrict__ xp2,
                      const float* __restrict__ bias, const float* __restrict__ w1,
                      const float* __restrict__ b1, __half* __restrict__ u,
                      __half* __restrict__ v) {
    int part = blockIdx.x & 7;
    int rank = blockIdx.x >> 3;
    int hwl = threadIdx.x >> 5;   // half-wave within block (0..7)
    int ch = threadIdx.x & 31;

    for (int n0 = rank * 8 + hwl; n0 < PART_N; n0 += AGG_K * 8) {
        int d = part * PART_N + n0;

        // self-loop term (fp32, once per node)
        float2 Ad  = ((const float2*)a_dst)[d];
        float2 As0 = ((const float2*)a_src)[d];
        float e0 = As0.x + Ad.x; e0 = (e0 > 0.f) ? e0 : NEG_SLOPE * e0;
        float e1 = As0.y + Ad.y; e1 = (e1 > 0.f) ? e1 : NEG_SLOPE * e1;
        float w00 = __expf(e0), w01 = __expf(e1);
        float2 xself = __half22float2(xp2[d * 32 + ch]);
        float num0 = w00 * xself.x, num1 = w01 * xself.y;
        float den0 = w00, den1 = w01;

        int base = goff(offs, partials, d);
        int cnt = goff(offs, partials, d + 1) - base;
        int last = (cnt > 0) ? (cnt - 1) : 0;

        constexpr int U = 8;
        int rounds = (cnt + U - 1) / U;
        for (int r = 0; r < rounds; r++) {
            int j = r * U;
            int2 rc[U];
#pragma unroll
            for (int k = 0; k < U; k++) {
                int jj = j + k;
                int cidx = (jj < cnt) ? jj : last;
                rc[k] = recs[base + cidx];
            }
            __half2 xv[U];
#pragma unroll
            for (int k = 0; k < U; k++)
                xv[k] = xp2[rc[k].x * 32 + ch];
            __half2 nblk = __floats2half2_rn(0.f, 0.f);
            __half2 dblk = nblk;
#pragma unroll
            for (int k = 0; k < U; k++) {
                int wb = (j + k < cnt) ? rc[k].y : 0;   // masks clamped tail dups
                __half2 w = bits_to_h2(wb);
                dblk = __hadd2(dblk, w);
                nblk = __hfma2(w, xv[k], nblk);
            }
            float2 nf = __half22float2(nblk);
            float2 df = __half22float2(dblk);
            num0 += nf.x; num1 += nf.y;
            den0 += df.x; den1 += df.y;
        }

        // head mean + bias: lane c holds full h[c] (both heads local)
        float h = 0.5f * (num0 / (den0 + 1e-16f) + num1 / (den1 + 1e-16f)) + bias[ch];

        // fused MLP factorization: width-32 shfl broadcast within half-wave
        float uu = b1[ch], vv = 0.f;
#pragma unroll
        for (int c = 0; c < 32; c++) {
            float hc = __shfl(h, c, 32);
            uu += hc * w1[c * 32 + ch];
            vv += hc * w1[(32 + c) * 32 + ch];
        }
        u[d * 32 + ch] = __float2half(uu);
        v[d * 32 + ch] = __float2half(vv);
    }
}

// ---------------------------------------------------------------------------
// K6: per-edge logits in original edge order (coalesced out writes),
//     2 edges/thread. u/v fp16 rows gathered; packed-half2 dot, fp32 combine.
// ---------------------------------------------------------------------------
__global__ void k_mlp(const int* __restrict__ src, const int* __restrict__ dst,
                      const __half2* __restrict__ u2, const __half2* __restrict__ v2,
                      const __half2* __restrict__ w2h, const float* __restrict__ b2,
                      float* __restrict__ out) {
    int t = blockIdx.x * blockDim.x + threadIdx.x;
    if (t >= MLP_T) return;
    __half2 wl[16];
#pragma unroll
    for (int q = 0; q < 4; q++) ((float4*)wl)[q] = ((const float4*)w2h)[q];
    int s[MLP_B], d[MLP_B];
#pragma unroll
    for (int k = 0; k < MLP_B; k++) {
        s[k] = src[t + k * MLP_T];
        d[k] = dst[t + k * MLP_T];
    }
    float4 ua[MLP_B][4], va[MLP_B][4];
#pragma unroll
    for (int k = 0; k < MLP_B; k++) {
        const float4* up4 = (const float4*)(u2 + s[k] * 16);
        const float4* vp4 = (const float4*)(v2 + d[k] * 16);
#pragma unroll
        for (int q = 0; q < 4; q++) { ua[k][q] = up4[q]; va[k][q] = vp4[q]; }
    }
#pragma unroll
    for (int k = 0; k < MLP_B; k++) {
        const __half2* uh = (const __half2*)ua[k];
        const __half2* vh = (const __half2*)va[k];
        const __half2 z2 = __floats2half2_rn(0.f, 0.f);
        __half2 acc0 = z2, acc1 = z2, acc2 = z2, acc3 = z2;
#pragma unroll
        for (int q = 0; q < 16; q += 4) {
            acc0 = __hfma2(h2_relu(__hadd2(uh[q + 0], vh[q + 0])), wl[q + 0], acc0);
            acc1 = __hfma2(h2_relu(__hadd2(uh[q + 1], vh[q + 1])), wl[q + 1], acc1);
            acc2 = __hfma2(h2_relu(__hadd2(uh[q + 2], vh[q + 2])), wl[q + 2], acc2);
            acc3 = __hfma2(h2_relu(__hadd2(uh[q + 3], vh[q + 3])), wl[q + 3], acc3);
        }
        float2 f0 = __half22float2(acc0);
        float2 f1 = __half22float2(acc1);
        float2 f2 = __half22float2(acc2);
        float2 f3 = __half22float2(acc3);
        float acc = b2[0] + (f0.x + f0.y) + (f1.x + f1.y) + (f2.x + f2.y) + (f3.x + f3.y);
        out[t + k * MLP_T] = acc * INV_TEMP;
    }
}

// ---------------------------------------------------------------------------
extern "C" void kernel_launch(void* const* d_in, const int* in_sizes, int n_in,
                              void* d_out, int out_size, void* d_ws, size_t ws_size,
                              hipStream_t stream) {
    const float* x       = (const float*)d_in[0];
    const int*   eidx    = (const int*)d_in[1];          // [2,E] int32
    const float* W       = (const float*)d_in[2];
    const float* att_src = (const float*)d_in[3];
    const float* att_dst = (const float*)d_in[4];
    const float* bias    = (const float*)d_in[5];
    const float* w1      = (const float*)d_in[6];
    const float* b1      = (const float*)d_in[7];
    const float* w2      = (const float*)d_in[8];
    const float* b2      = (const float*)d_in[9];
    float* out = (float*)d_out;

    const int* src = eidx;             // row 0
    const int* dst = eidx + E_EDGES;   // row 1

    // Workspace layout (~40 MB total; 16B alignment holds at each boundary).
    int* counts   = (int*)d_ws;                      // N (zeroed in k_node)
    int* offs     = counts + N_NODES;                // N
    int* partials = offs + N_NODES;                  // 128
    __half2* w2h  = (__half2*)(partials + 128);      // 16 half2 (64 B)
    int2* recs    = (int2*)(w2h + 16);               // E 8-B records (12.8 MB)
    float* a_src  = (float*)(recs + E_EDGES);        // 2N
    float* a_dst  = a_src + 2 * N_NODES;             // 2N
    __half2* xp2  = (__half2*)(a_dst + 2 * N_NODES); // 32N half2 (12.8 MB)
    __half* u     = (__half*)(xp2 + 32 * (size_t)N_NODES);  // 32N halves (6.4 MB)
    __half* v     = u + 32 * (size_t)N_NODES;               // 32N halves (6.4 MB)

    constexpr int BS = 256;

    // K1: node transform (+ counts zero, fused)
    k_node<<<(N_NODES + BS - 1) / BS, BS, 0, stream>>>(x, W, att_src, att_dst,
                                                      xp2, a_src, a_dst, counts);

    // K2: degree histogram (XCD-partitioned)
    k_hist<<<NPART * HIST_K, BS, 0, stream>>>(dst, counts);

    // K3: exclusive scan counts -> offs (chunk-local) + chunk bases; pack w2
    k_scan1<<<NCHUNK, 256, 0, stream>>>(counts, offs, partials);
    k_scan2<<<1, 128, 0, stream>>>(partials, w2, w2h);

    // K4: CSR placement + attention weights (XCD-partitioned, cursor-free)
    k_place<<<NPART * PLACE_K, BS, 0, stream>>>(src, dst, offs, partials,
                                                a_src, a_dst, counts, recs);

    // K5: aggregation + fused MLP factorization (XCD-partitioned)
    k_agg<<<NPART * AGG_K, BS, 0, stream>>>(recs, offs, partials, a_src, a_dst,
                                            xp2, bias, w1, b1, u, v);

    // K6: per-edge logits (edge order, 2 edges/thread)
    k_mlp<<<(MLP_T + BS - 1) / BS, BS, 0, stream>>>(src, dst, (const __half2*)u,
                                                   (const __half2*)v, w2h, b2, out);
}

// Round 10
// 356.747 us; speedup vs baseline: 1.0483x; 1.0469x over previous
//
#include <hip/hip_runtime.h>
#include <hip/hip_fp16.h>
#include <cstdint>

// Problem constants (match reference)
constexpr int N_NODES = 100000;
constexpr int E_EDGES = 1600000;
constexpr float NEG_SLOPE = 0.2f;
constexpr float INV_TEMP = 1.0f / 0.7f;

// Partition/bucket geometry
constexpr int NPART = 8;
constexpr int PART_N = N_NODES / NPART;          // 12500
constexpr int BKT_NODES = 128;                   // nodes per bucket
constexpr int NBKT_PART = (PART_N + BKT_NODES - 1) / BKT_NODES;  // 98
constexpr int NBKT = NPART * NBKT_PART;          // 784
constexpr int REG = 3072;                        // rec capacity per bucket (mean 2041, 23 sigma)
constexpr int TILE = 16384;                      // edges scanned per k_split tile
constexpr int CAPK = 2560;                       // kept-per-tile cap (mean 2048, 12 sigma)
constexpr int RANKS = 32;                        // blocks per partition in k_split
constexpr int NTILES = (E_EDGES + TILE - 1) / TILE;  // 98

constexpr int MLP_B = 2;
constexpr int MLP_T = E_EDGES / MLP_B;           // 800000

__device__ __forceinline__ __half2 bits_to_h2(int bits) {
    return *reinterpret_cast<__half2*>(&bits);
}

// packed relu (no __hmax2 in ROCm 7.2 headers; __hgt2 gives packed 1/0 mask)
__device__ __forceinline__ __half2 h2_relu(__half2 a) {
    const __half2 z = __floats2half2_rn(0.f, 0.f);
    return __hmul2(a, __hgt2(a, z));
}

// ---------------------------------------------------------------------------
// K1: per-node transform. xp2[n][c] = half2(head0_c, head1_c); a_src/a_dst
//     dots [N,2] fp32. Fused: zero gcur[784], pack w2 -> w2h[16].
// ---------------------------------------------------------------------------
__global__ void k_node(const float* __restrict__ x, const float* __restrict__ W,
                       const float* __restrict__ att_src, const float* __restrict__ att_dst,
                       __half2* __restrict__ xp2, float* __restrict__ a_src,
                       float* __restrict__ a_dst, int* __restrict__ gcur,
                       const float* __restrict__ w2, __half2* __restrict__ w2h) {
    int n = blockIdx.x * blockDim.x + threadIdx.x;
    if (blockIdx.x == 0 && threadIdx.x < 16)
        w2h[threadIdx.x] = __floats2half2_rn(w2[2 * threadIdx.x], w2[2 * threadIdx.x + 1]);
    if (n < NBKT) gcur[n] = 0;
    if (n >= N_NODES) return;
    float xi[16];
    const float4* xv = (const float4*)(x + (size_t)n * 16);
    ((float4*)xi)[0] = xv[0];
    ((float4*)xi)[1] = xv[1];
    ((float4*)xi)[2] = xv[2];
    ((float4*)xi)[3] = xv[3];
    float as0 = 0.f, as1 = 0.f, ad0 = 0.f, ad1 = 0.f;
    __half2 hbuf[32];
#pragma unroll
    for (int c = 0; c < 32; c++) {
        float acc0 = 0.f, acc1 = 0.f;
#pragma unroll
        for (int k = 0; k < 16; k++) {
            acc0 += xi[k] * W[k * 64 + c];
            acc1 += xi[k] * W[k * 64 + 32 + c];
        }
        hbuf[c] = __floats2half2_rn(acc0, acc1);
        as0 += acc0 * att_src[c];
        as1 += acc1 * att_src[32 + c];
        ad0 += acc0 * att_dst[c];
        ad1 += acc1 * att_dst[32 + c];
    }
    float4* dst4 = (float4*)(xp2 + (size_t)n * 32);
#pragma unroll
    for (int q = 0; q < 8; q++) dst4[q] = ((float4*)hbuf)[q];
    ((float2*)a_src)[n] = make_float2(as0, as1);
    ((float2*)a_dst)[n] = make_float2(ad0, ad1);
}

// ---------------------------------------------------------------------------
// K2 (k_split): edges -> bucketed records with LDS-staged counting sort so
//     ALL global writes are line-sized coalesced segments.
//     Block (part, rank) scans tiles of 16384 edges, keeps d in its
//     partition, computes w = exp(leakyrelu(a)), appends {s|dloc<<17, wbits}
//     to LDS; per tile: 98-bucket histogram, scan, one global atomic per
//     bucket to reserve, LDS rank-scatter, coalesced segment writes.
// ---------------------------------------------------------------------------
__global__ void __launch_bounds__(256) k_split(
        const int* __restrict__ src, const int* __restrict__ dst,
        const float* __restrict__ a_src, const float* __restrict__ a_dst,
        int* __restrict__ gcur, int2* __restrict__ recs_g) {
    __shared__ int2 lrec[CAPK];
    __shared__ unsigned short lidx[CAPK];
    __shared__ int hist[NBKT_PART];
    __shared__ int sc[128];
    __shared__ int cnt2[NBKT_PART];
    __shared__ int gbase[NBKT_PART];
    __shared__ int kcnt;

    int part = blockIdx.x & 7;
    int rank = blockIdx.x >> 3;
    int tid = threadIdx.x;
    int lo = part * PART_N, hi = lo + PART_N;

    for (int tile = rank; tile < NTILES; tile += RANKS) {
        int ebase = tile * TILE;
        if (tid == 0) kcnt = 0;
        if (tid < NBKT_PART) { hist[tid] = 0; cnt2[tid] = 0; }
        if (tid < 128) sc[tid] = 0;
        __syncthreads();

        // phase 1: scan 64 edges/thread (16 x int4), keep partition's edges
        for (int it = 0; it < TILE / (256 * 4); it++) {
            int e4 = ebase + (it * 256 + tid) * 4;
            int dd[4], ss[4], nvalid = 0;
            if (e4 + 3 < E_EDGES) {
                int4 d4 = *(const int4*)(dst + e4);
                int4 s4 = *(const int4*)(src + e4);
                dd[0] = d4.x; dd[1] = d4.y; dd[2] = d4.z; dd[3] = d4.w;
                ss[0] = s4.x; ss[1] = s4.y; ss[2] = s4.z; ss[3] = s4.w;
                nvalid = 4;
            } else if (e4 < E_EDGES) {
                nvalid = E_EDGES - e4;
                for (int k = 0; k < nvalid; k++) { dd[k] = dst[e4 + k]; ss[k] = src[e4 + k]; }
            }
            for (int k = 0; k < nvalid; k++) {
                int d = dd[k];
                if (d >= lo && d < hi) {
                    int s = ss[k];
                    float2 As = ((const float2*)a_src)[s];
                    float2 Ad = ((const float2*)a_dst)[d];
                    float e0 = As.x + Ad.x; e0 = (e0 > 0.f) ? e0 : NEG_SLOPE * e0;
                    float e1 = As.y + Ad.y; e1 = (e1 > 0.f) ? e1 : NEG_SLOPE * e1;
                    __half2 hw = __floats2half2_rn(__expf(e0), __expf(e1));
                    int wb = *reinterpret_cast<int*>(&hw);
                    int kp = atomicAdd(&kcnt, 1);
                    if (kp < CAPK) lrec[kp] = make_int2(s | ((d - lo) << 17), wb);
                }
            }
        }
        __syncthreads();
        int kc = kcnt; if (kc > CAPK) kc = CAPK;

        // phase 2: histogram by bucket (= dloc>>7 = rec.x>>24)
        for (int i = tid; i < kc; i += 256)
            atomicAdd(&hist[lrec[i].x >> 24], 1);
        __syncthreads();

        // phase 3: inclusive scan of hist into sc (Hillis-Steele over 128)
        if (tid < NBKT_PART) sc[tid] = hist[tid];
        __syncthreads();
        for (int off = 1; off < 128; off <<= 1) {
            int v = (tid < 128 && tid >= off) ? sc[tid - off] : 0;
            __syncthreads();
            if (tid < 128) sc[tid] += v;
            __syncthreads();
        }

        // phase 4: reserve global space (one atomic per bucket per tile)
        if (tid < NBKT_PART)
            gbase[tid] = atomicAdd(&gcur[part * NBKT_PART + tid], hist[tid]);
        __syncthreads();

        // phase 5: rank-scatter indices into bucket-grouped order (LDS only)
        for (int i = tid; i < kc; i += 256) {
            int b = lrec[i].x >> 24;
            int r = atomicAdd(&cnt2[b], 1);
            int base = (b > 0) ? sc[b - 1] : 0;
            lidx[base + r] = (unsigned short)i;
        }
        __syncthreads();

        // phase 6: coalesced segment writes (consecutive i in a bucket ->
        // consecutive global addresses)
        for (int i = tid; i < kc; i += 256) {
            int2 rc = lrec[lidx[i]];
            int b = rc.x >> 24;
            int base = (b > 0) ? sc[b - 1] : 0;
            int gpos = gbase[b] + (i - base);
            if (gpos < REG)
                recs_g[(size_t)(part * NBKT_PART + b) * REG + gpos] = rc;
        }
        __syncthreads();   // LDS reused next tile
    }
}

// ---------------------------------------------------------------------------
// K3 (k_aggsort): one block per bucket (128 nodes). Load bucket records
//     coalesced -> LDS counting sort by node (u16 idx only) -> half-wave-
//     per-node packed-half2 aggregation (records via LDS broadcast) ->
//     fused u/v MLP-factorization epilogue.
// ---------------------------------------------------------------------------
__global__ void __launch_bounds__(256) k_aggsort(
        const int2* __restrict__ recs_g, const int* __restrict__ gcur,
        const float* __restrict__ a_src, const float* __restrict__ a_dst,
        const __half2* __restrict__ xp2, const float* __restrict__ bias,
        const float* __restrict__ w1, const float* __restrict__ b1,
        __half* __restrict__ u, __half* __restrict__ v) {
    __shared__ int2 lrec[REG];             // 24 KB
    __shared__ unsigned short lidx[REG];   // 6 KB
    __shared__ int hist[BKT_NODES];
    __shared__ int sc[BKT_NODES];
    __shared__ int cnt2[BKT_NODES];

    int gb = blockIdx.x;
    int part = gb / NBKT_PART;
    int lb = gb - part * NBKT_PART;
    int node0 = part * PART_N + lb * BKT_NODES;
    int nnodes = PART_N - lb * BKT_NODES;
    if (nnodes > BKT_NODES) nnodes = BKT_NODES;
    int tid = threadIdx.x;
    int cnt = gcur[gb]; if (cnt > REG) cnt = REG;
    const int2* breg = recs_g + (size_t)gb * REG;

    if (tid < BKT_NODES) { hist[tid] = 0; cnt2[tid] = 0; }
    __syncthreads();
    for (int i = tid; i < cnt; i += 256) lrec[i] = breg[i];
    __syncthreads();
    for (int i = tid; i < cnt; i += 256)
        atomicAdd(&hist[(lrec[i].x >> 17) & 127], 1);
    __syncthreads();
    if (tid < BKT_NODES) sc[tid] = hist[tid];
    __syncthreads();
    for (int off = 1; off < BKT_NODES; off <<= 1) {
        int vv = (tid < BKT_NODES && tid >= off) ? sc[tid - off] : 0;
        __syncthreads();
        if (tid < BKT_NODES) sc[tid] += vv;
        __syncthreads();
    }
    for (int i = tid; i < cnt; i += 256) {
        int n7 = (lrec[i].x >> 17) & 127;
        int r = atomicAdd(&cnt2[n7], 1);
        int base = (n7 > 0) ? sc[n7 - 1] : 0;
        lidx[base + r] = (unsigned short)i;
    }
    __syncthreads();

    // aggregation: 8 half-waves, up to 16 nodes each
    int hwl = tid >> 5, ch = tid & 31;
    for (int nl = hwl; nl < nnodes; nl += 8) {
        int d = node0 + nl;

        // self-loop term (fp32)
        float2 Ad  = ((const float2*)a_dst)[d];
        float2 As0 = ((const float2*)a_src)[d];
        float e0 = As0.x + Ad.x; e0 = (e0 > 0.f) ? e0 : NEG_SLOPE * e0;
        float e1 = As0.y + Ad.y; e1 = (e1 > 0.f) ? e1 : NEG_SLOPE * e1;
        float w00 = __expf(e0), w01 = __expf(e1);
        float2 xself = __half22float2(xp2[d * 32 + ch]);
        float num0 = w00 * xself.x, num1 = w01 * xself.y;
        float den0 = w00, den1 = w01;

        int start = (nl > 0) ? sc[nl - 1] : 0;
        int cn = hist[nl];
        int last = (cn > 0) ? (cn - 1) : 0;

        constexpr int U = 8;
        int rounds = (cn + U - 1) / U;
        for (int r = 0; r < rounds; r++) {
            int j = r * U;
            int2 rc[U];
#pragma unroll
            for (int k = 0; k < U; k++) {
                int jj = j + k;
                int cidx = (jj < cn) ? jj : last;
                rc[k] = lrec[lidx[start + cidx]];   // LDS broadcast reads
            }
            __half2 xv[U];
#pragma unroll
            for (int k = 0; k < U; k++)
                xv[k] = xp2[(rc[k].x & 0x1FFFF) * 32 + ch];
            __half2 nblk = __floats2half2_rn(0.f, 0.f);
            __half2 dblk = nblk;
#pragma unroll
            for (int k = 0; k < U; k++) {
                int wb = (j + k < cn) ? rc[k].y : 0;   // masks tail dups
                __half2 w = bits_to_h2(wb);
                dblk = __hadd2(dblk, w);
                nblk = __hfma2(w, xv[k], nblk);
            }
            float2 nf = __half22float2(nblk);
            float2 df = __half22float2(dblk);
            num0 += nf.x; num1 += nf.y;
            den0 += df.x; den1 += df.y;
        }

        float h = 0.5f * (num0 / (den0 + 1e-16f) + num1 / (den1 + 1e-16f)) + bias[ch];

        float uu = b1[ch], vv = 0.f;
#pragma unroll
        for (int c = 0; c < 32; c++) {
            float hc = __shfl(h, c, 32);
            uu += hc * w1[c * 32 + ch];
            vv += hc * w1[(32 + c) * 32 + ch];
        }
        u[d * 32 + ch] = __float2half(uu);
        v[d * 32 + ch] = __float2half(vv);
    }
}

// ---------------------------------------------------------------------------
// K4: per-edge logits in original edge order (coalesced out writes),
//     2 edges/thread. u/v fp16 rows gathered; packed-half2 dot, fp32 combine.
// ---------------------------------------------------------------------------
__global__ void k_mlp(const int* __restrict__ src, const int* __restrict__ dst,
                      const __half2* __restrict__ u2, const __half2* __restrict__ v2,
                      const __half2* __restrict__ w2h, const float* __restrict__ b2,
                      float* __restrict__ out) {
    int t = blockIdx.x * blockDim.x + threadIdx.x;
    if (t >= MLP_T) return;
    __half2 wl[16];
#pragma unroll
    for (int q = 0; q < 4; q++) ((float4*)wl)[q] = ((const float4*)w2h)[q];
    int s[MLP_B], d[MLP_B];
#pragma unroll
    for (int k = 0; k < MLP_B; k++) {
        s[k] = src[t + k * MLP_T];
        d[k] = dst[t + k * MLP_T];
    }
    float4 ua[MLP_B][4], va[MLP_B][4];
#pragma unroll
    for (int k = 0; k < MLP_B; k++) {
        const float4* up4 = (const float4*)(u2 + s[k] * 16);
        const float4* vp4 = (const float4*)(v2 + d[k] * 16);
#pragma unroll
        for (int q = 0; q < 4; q++) { ua[k][q] = up4[q]; va[k][q] = vp4[q]; }
    }
#pragma unroll
    for (int k = 0; k < MLP_B; k++) {
        const __half2* uh = (const __half2*)ua[k];
        const __half2* vh = (const __half2*)va[k];
        const __half2 z2 = __floats2half2_rn(0.f, 0.f);
        __half2 acc0 = z2, acc1 = z2, acc2 = z2, acc3 = z2;
#pragma unroll
        for (int q = 0; q < 16; q += 4) {
            acc0 = __hfma2(h2_relu(__hadd2(uh[q + 0], vh[q + 0])), wl[q + 0], acc0);
            acc1 = __hfma2(h2_relu(__hadd2(uh[q + 1], vh[q + 1])), wl[q + 1], acc1);
            acc2 = __hfma2(h2_relu(__hadd2(uh[q + 2], vh[q + 2])), wl[q + 2], acc2);
            acc3 = __hfma2(h2_relu(__hadd2(uh[q + 3], vh[q + 3])), wl[q + 3], acc3);
        }
        float2 f0 = __half22float2(acc0);
        float2 f1 = __half22float2(acc1);
        float2 f2 = __half22float2(acc2);
        float2 f3 = __half22float2(acc3);
        float acc = b2[0] + (f0.x + f0.y) + (f1.x + f1.y) + (f2.x + f2.y) + (f3.x + f3.y);
        out[t + k * MLP_T] = acc * INV_TEMP;
    }
}

// ---------------------------------------------------------------------------
extern "C" void kernel_launch(void* const* d_in, const int* in_sizes, int n_in,
                              void* d_out, int out_size, void* d_ws, size_t ws_size,
                              hipStream_t stream) {
    const float* x       = (const float*)d_in[0];
    const int*   eidx    = (const int*)d_in[1];          // [2,E] int32
    const float* W       = (const float*)d_in[2];
    const float* att_src = (const float*)d_in[3];
    const float* att_dst = (const float*)d_in[4];
    const float* bias    = (const float*)d_in[5];
    const float* w1      = (const float*)d_in[6];
    const float* b1      = (const float*)d_in[7];
    const float* w2      = (const float*)d_in[8];
    const float* b2      = (const float*)d_in[9];
    float* out = (float*)d_out;

    const int* src = eidx;             // row 0
    const int* dst = eidx + E_EDGES;   // row 1

    // Workspace layout (~47 MB; 16B alignment holds at each boundary).
    int* gcur     = (int*)d_ws;                      // 784 (zeroed in k_node)
    __half2* w2h  = (__half2*)(gcur + 784);          // 16 half2 (64 B)
    int2* recs_g  = (int2*)(w2h + 16);               // NBKT*REG recs (19.3 MB)
    float* a_src  = (float*)(recs_g + (size_t)NBKT * REG);  // 2N
    float* a_dst  = a_src + 2 * N_NODES;             // 2N
    __half2* xp2  = (__half2*)(a_dst + 2 * N_NODES); // 32N half2 (12.8 MB)
    __half* u     = (__half*)(xp2 + 32 * (size_t)N_NODES);  // 32N halves (6.4 MB)
    __half* v     = u + 32 * (size_t)N_NODES;               // 32N halves (6.4 MB)

    constexpr int BS = 256;

    // K1: node transform (+ gcur zero + w2 pack, fused)
    k_node<<<(N_NODES + BS - 1) / BS, BS, 0, stream>>>(x, W, att_src, att_dst,
                                                      xp2, a_src, a_dst, gcur, w2, w2h);

    // K2: LDS-staged bucket split (coalesced record writes)
    k_split<<<NPART * RANKS, BS, 0, stream>>>(src, dst, a_src, a_dst, gcur, recs_g);

    // K3: per-bucket LDS sort + aggregation + fused MLP factorization
    k_aggsort<<<NBKT, BS, 0, stream>>>(recs_g, gcur, a_src, a_dst, xp2,
                                       bias, w1, b1, u, v);

    // K4: per-edge logits (edge order, 2 edges/thread)
    k_mlp<<<(MLP_T + BS - 1) / BS, BS, 0, stream>>>(src, dst, (const __half2*)u,
                                                   (const __half2*)v, w2h, b2, out);
}

// Round 11
// 269.709 us; speedup vs baseline: 1.3866x; 1.3227x over previous
//
#include <hip/hip_runtime.h>
#include <hip/hip_fp16.h>
#include <cstdint>

// Problem constants (match reference)
constexpr int N_NODES = 100000;
constexpr int E_EDGES = 1600000;
constexpr float NEG_SLOPE = 0.2f;
constexpr float INV_TEMP = 1.0f / 0.7f;

// Partition/bucket geometry
constexpr int NPART = 8;
constexpr int PART_N = N_NODES / NPART;          // 12500
constexpr int BKT_NODES = 64;                    // nodes per bucket
constexpr int NBKT_PART = (PART_N + BKT_NODES - 1) / BKT_NODES;  // 196
constexpr int NBKT = NPART * NBKT_PART;          // 1568
constexpr int REG_B = 1792;                      // recs per bucket (mean 1024, +17 sigma)
constexpr int THALF = 8192;                      // edges per k_split tile
constexpr int NTH = (E_EDGES + THALF - 1) / THALF;  // 196
constexpr int CAPK = 1344;                       // kept per (part,tile): mean 1024, +10.6 sigma

constexpr int MLP_B = 2;
constexpr int MLP_T = E_EDGES / MLP_B;           // 800000

__device__ __forceinline__ __half2 bits_to_h2(int bits) {
    return *reinterpret_cast<__half2*>(&bits);
}

// packed relu (no __hmax2 in ROCm 7.2 headers; __hgt2 gives packed 1/0 mask)
__device__ __forceinline__ __half2 h2_relu(__half2 a) {
    const __half2 z = __floats2half2_rn(0.f, 0.f);
    return __hmul2(a, __hgt2(a, z));
}

// ---------------------------------------------------------------------------
// K1: per-node transform. xp2[n][c] = half2(head0_c, head1_c); a_src/a_dst
//     dots [N,2] fp32. Fused: zero gcur[1568], pack w2 -> w2h[16].
// ---------------------------------------------------------------------------
__global__ void k_node(const float* __restrict__ x, const float* __restrict__ W,
                       const float* __restrict__ att_src, const float* __restrict__ att_dst,
                       __half2* __restrict__ xp2, float* __restrict__ a_src,
                       float* __restrict__ a_dst, int* __restrict__ gcur,
                       const float* __restrict__ w2, __half2* __restrict__ w2h) {
    int n = blockIdx.x * blockDim.x + threadIdx.x;
    if (blockIdx.x == 0 && threadIdx.x < 16)
        w2h[threadIdx.x] = __floats2half2_rn(w2[2 * threadIdx.x], w2[2 * threadIdx.x + 1]);
    if (n < NBKT) gcur[n] = 0;
    if (n >= N_NODES) return;
    float xi[16];
    const float4* xv = (const float4*)(x + (size_t)n * 16);
    ((float4*)xi)[0] = xv[0];
    ((float4*)xi)[1] = xv[1];
    ((float4*)xi)[2] = xv[2];
    ((float4*)xi)[3] = xv[3];
    float as0 = 0.f, as1 = 0.f, ad0 = 0.f, ad1 = 0.f;
    __half2 hbuf[32];
#pragma unroll
    for (int c = 0; c < 32; c++) {
        float acc0 = 0.f, acc1 = 0.f;
#pragma unroll
        for (int k = 0; k < 16; k++) {
            acc0 += xi[k] * W[k * 64 + c];
            acc1 += xi[k] * W[k * 64 + 32 + c];
        }
        hbuf[c] = __floats2half2_rn(acc0, acc1);
        as0 += acc0 * att_src[c];
        as1 += acc1 * att_src[32 + c];
        ad0 += acc0 * att_dst[c];
        ad1 += acc1 * att_dst[32 + c];
    }
    float4* dst4 = (float4*)(xp2 + (size_t)n * 32);
#pragma unroll
    for (int q = 0; q < 8; q++) dst4[q] = ((float4*)hbuf)[q];
    ((float2*)a_src)[n] = make_float2(as0, as1);
    ((float2*)a_dst)[n] = make_float2(ad0, ad1);
}

// ---------------------------------------------------------------------------
// K2 (k_split): one block per (partition, 8192-edge tile). Two-pass LDS
//     counting sort (no append serialization):
//       A: dst-only histogram over 196 buckets
//       scan (256-wide Hillis-Steele) + global space reservation
//       B: re-read edges (L2-hot), compute w, write record to sorted LDS slot
//       C: coalesced segment write-out
//     Record: {s | dloc<<17, half2(w0,w1)}  (s<2^17, dloc<2^14)
// ---------------------------------------------------------------------------
__global__ void __launch_bounds__(256) k_split(
        const int* __restrict__ src, const int* __restrict__ dst,
        const float* __restrict__ a_src, const float* __restrict__ a_dst,
        int* __restrict__ gcur, int2* __restrict__ recs_g) {
    __shared__ int2 lrec[CAPK];        // 10.8 KB
    __shared__ int hist[256];          // 196 used, padded for scan
    __shared__ int sc[256];
    __shared__ int cnt2[NBKT_PART];
    __shared__ int gbase[NBKT_PART];

    int part = blockIdx.x & 7;
    int th = blockIdx.x >> 3;          // 0..195
    int tid = threadIdx.x;
    int lo = part * PART_N, hi = lo + PART_N;
    int ebase = th * THALF;

    hist[tid] = 0;
    if (tid < NBKT_PART) cnt2[tid] = 0;
    __syncthreads();

    // pass A: histogram (dst row only)
#pragma unroll
    for (int it = 0; it < THALF / (256 * 4); it++) {
        int e4 = ebase + (it * 256 + tid) * 4;
        if (e4 + 3 < E_EDGES) {
            int4 d4 = *(const int4*)(dst + e4);
            if (d4.x >= lo && d4.x < hi) atomicAdd(&hist[(d4.x - lo) >> 6], 1);
            if (d4.y >= lo && d4.y < hi) atomicAdd(&hist[(d4.y - lo) >> 6], 1);
            if (d4.z >= lo && d4.z < hi) atomicAdd(&hist[(d4.z - lo) >> 6], 1);
            if (d4.w >= lo && d4.w < hi) atomicAdd(&hist[(d4.w - lo) >> 6], 1);
        } else if (e4 < E_EDGES) {
            int nv = E_EDGES - e4;
            for (int k = 0; k < nv; k++) {
                int d = dst[e4 + k];
                if (d >= lo && d < hi) atomicAdd(&hist[(d - lo) >> 6], 1);
            }
        }
    }
    __syncthreads();

    // inclusive scan hist -> sc (256-wide)
    sc[tid] = hist[tid];
    __syncthreads();
    for (int off = 1; off < 256; off <<= 1) {
        int v = (tid >= off) ? sc[tid - off] : 0;
        __syncthreads();
        sc[tid] += v;
        __syncthreads();
    }

    // reserve global space (one atomic per bucket per block)
    if (tid < NBKT_PART)
        gbase[tid] = atomicAdd(&gcur[part * NBKT_PART + tid], hist[tid]);
    __syncthreads();

    // pass B: compute weights, write to sorted LDS slots
#pragma unroll
    for (int it = 0; it < THALF / (256 * 4); it++) {
        int e4 = ebase + (it * 256 + tid) * 4;
        int dd[4], ss[4], nv = 0;
        if (e4 + 3 < E_EDGES) {
            int4 d4 = *(const int4*)(dst + e4);
            int4 s4 = *(const int4*)(src + e4);
            dd[0] = d4.x; dd[1] = d4.y; dd[2] = d4.z; dd[3] = d4.w;
            ss[0] = s4.x; ss[1] = s4.y; ss[2] = s4.z; ss[3] = s4.w;
            nv = 4;
        } else if (e4 < E_EDGES) {
            nv = E_EDGES - e4;
            for (int k = 0; k < nv; k++) { dd[k] = dst[e4 + k]; ss[k] = src[e4 + k]; }
        }
        for (int k = 0; k < nv; k++) {
            int d = dd[k];
            if (d >= lo && d < hi) {
                int s = ss[k];
                float2 As = ((const float2*)a_src)[s];
                float2 Ad = ((const float2*)a_dst)[d];
                float e0 = As.x + Ad.x; e0 = (e0 > 0.f) ? e0 : NEG_SLOPE * e0;
                float e1 = As.y + Ad.y; e1 = (e1 > 0.f) ? e1 : NEG_SLOPE * e1;
                __half2 hw = __floats2half2_rn(__expf(e0), __expf(e1));
                int wb = *reinterpret_cast<int*>(&hw);
                int dloc = d - lo;
                int b = dloc >> 6;
                int posl = ((b > 0) ? sc[b - 1] : 0) + atomicAdd(&cnt2[b], 1);
                if (posl < CAPK) lrec[posl] = make_int2(s | (dloc << 17), wb);
            }
        }
    }
    __syncthreads();

    // pass C: coalesced segment write-out
    int kc = sc[NBKT_PART - 1]; if (kc > CAPK) kc = CAPK;
    for (int i = tid; i < kc; i += 256) {
        int2 rc = lrec[i];
        int b = rc.x >> 23;                       // dloc>>6
        int excl = (b > 0) ? sc[b - 1] : 0;
        int gpos = gbase[b] + (i - excl);
        if (gpos < REG_B)
            recs_g[(size_t)(part * NBKT_PART + b) * REG_B + gpos] = rc;
    }
}

// ---------------------------------------------------------------------------
// K3 (k_aggsort): one block per 64-node bucket. Coalesced record load ->
//     LDS counting sort by node (u16 idx) -> 8 half-waves x 8 nodes packed-
//     half2 aggregation -> fused u/v MLP-factorization epilogue.
// ---------------------------------------------------------------------------
__global__ void __launch_bounds__(256) k_aggsort(
        const int2* __restrict__ recs_g, const int* __restrict__ gcur,
        const float* __restrict__ a_src, const float* __restrict__ a_dst,
        const __half2* __restrict__ xp2, const float* __restrict__ bias,
        const float* __restrict__ w1, const float* __restrict__ b1,
        __half* __restrict__ u, __half* __restrict__ v) {
    __shared__ int2 lrec[REG_B];             // 14.3 KB
    __shared__ unsigned short lidx[REG_B];   // 3.6 KB
    __shared__ int hist[BKT_NODES];
    __shared__ int sc[BKT_NODES];
    __shared__ int cnt2[BKT_NODES];

    int gb = blockIdx.x;
    int part = gb / NBKT_PART;
    int lb = gb - part * NBKT_PART;
    int node0 = part * PART_N + lb * BKT_NODES;
    int nnodes = PART_N - lb * BKT_NODES;
    if (nnodes > BKT_NODES) nnodes = BKT_NODES;
    int tid = threadIdx.x;
    int cnt = gcur[gb]; if (cnt > REG_B) cnt = REG_B;
    const int2* breg = recs_g + (size_t)gb * REG_B;

    if (tid < BKT_NODES) { hist[tid] = 0; cnt2[tid] = 0; }
    __syncthreads();
    for (int i = tid; i < cnt; i += 256) lrec[i] = breg[i];
    __syncthreads();
    for (int i = tid; i < cnt; i += 256)
        atomicAdd(&hist[(lrec[i].x >> 17) & 63], 1);
    __syncthreads();
    if (tid < BKT_NODES) sc[tid] = hist[tid];
    __syncthreads();
    for (int off = 1; off < BKT_NODES; off <<= 1) {
        int vv = (tid < BKT_NODES && tid >= off) ? sc[tid - off] : 0;
        __syncthreads();
        if (tid < BKT_NODES) sc[tid] += vv;
        __syncthreads();
    }
    for (int i = tid; i < cnt; i += 256) {
        int n6 = (lrec[i].x >> 17) & 63;
        int r = atomicAdd(&cnt2[n6], 1);
        int base = (n6 > 0) ? sc[n6 - 1] : 0;
        lidx[base + r] = (unsigned short)i;
    }
    __syncthreads();

    int hwl = tid >> 5, ch = tid & 31;
    for (int nl = hwl; nl < nnodes; nl += 8) {
        int d = node0 + nl;

        // self-loop term (fp32)
        float2 Ad  = ((const float2*)a_dst)[d];
        float2 As0 = ((const float2*)a_src)[d];
        float e0 = As0.x + Ad.x; e0 = (e0 > 0.f) ? e0 : NEG_SLOPE * e0;
        float e1 = As0.y + Ad.y; e1 = (e1 > 0.f) ? e1 : NEG_SLOPE * e1;
        float w00 = __expf(e0), w01 = __expf(e1);
        float2 xself = __half22float2(xp2[d * 32 + ch]);
        float num0 = w00 * xself.x, num1 = w01 * xself.y;
        float den0 = w00, den1 = w01;

        int start = (nl > 0) ? sc[nl - 1] : 0;
        int cn = hist[nl];
        int last = (cn > 0) ? (cn - 1) : 0;

        constexpr int U = 8;
        int rounds = (cn + U - 1) / U;
        for (int r = 0; r < rounds; r++) {
            int j = r * U;
            int2 rc[U];
#pragma unroll
            for (int k = 0; k < U; k++) {
                int jj = j + k;
                int cidx = (jj < cn) ? jj : last;
                rc[k] = lrec[lidx[start + cidx]];   // LDS broadcast reads
            }
            __half2 xv[U];
#pragma unroll
            for (int k = 0; k < U; k++)
                xv[k] = xp2[(rc[k].x & 0x1FFFF) * 32 + ch];
            __half2 nblk = __floats2half2_rn(0.f, 0.f);
            __half2 dblk = nblk;
#pragma unroll
            for (int k = 0; k < U; k++) {
                int wb = (j + k < cn) ? rc[k].y : 0;   // masks tail dups
                __half2 w = bits_to_h2(wb);
                dblk = __hadd2(dblk, w);
                nblk = __hfma2(w, xv[k], nblk);
            }
            float2 nf = __half22float2(nblk);
            float2 df = __half22float2(dblk);
            num0 += nf.x; num1 += nf.y;
            den0 += df.x; den1 += df.y;
        }

        float h = 0.5f * (num0 / (den0 + 1e-16f) + num1 / (den1 + 1e-16f)) + bias[ch];

        float uu = b1[ch], vv = 0.f;
#pragma unroll
        for (int c = 0; c < 32; c++) {
            float hc = __shfl(h, c, 32);
            uu += hc * w1[c * 32 + ch];
            vv += hc * w1[(32 + c) * 32 + ch];
        }
        u[d * 32 + ch] = __float2half(uu);
        v[d * 32 + ch] = __float2half(vv);
    }
}

// ---------------------------------------------------------------------------
// K4: per-edge logits in original edge order (coalesced out writes),
//     2 edges/thread. u/v fp16 rows gathered; packed-half2 dot, fp32 combine.
// ---------------------------------------------------------------------------
__global__ void k_mlp(const int* __restrict__ src, const int* __restrict__ dst,
                      const __half2* __restrict__ u2, const __half2* __restrict__ v2,
                      const __half2* __restrict__ w2h, const float* __restrict__ b2,
                      float* __restrict__ out) {
    int t = blockIdx.x * blockDim.x + threadIdx.x;
    if (t >= MLP_T) return;
    __half2 wl[16];
#pragma unroll
    for (int q = 0; q < 4; q++) ((float4*)wl)[q] = ((const float4*)w2h)[q];
    int s[MLP_B], d[MLP_B];
#pragma unroll
    for (int k = 0; k < MLP_B; k++) {
        s[k] = src[t + k * MLP_T];
        d[k] = dst[t + k * MLP_T];
    }
    float4 ua[MLP_B][4], va[MLP_B][4];
#pragma unroll
    for (int k = 0; k < MLP_B; k++) {
        const float4* up4 = (const float4*)(u2 + s[k] * 16);
        const float4* vp4 = (const float4*)(v2 + d[k] * 16);
#pragma unroll
        for (int q = 0; q < 4; q++) { ua[k][q] = up4[q]; va[k][q] = vp4[q]; }
    }
#pragma unroll
    for (int k = 0; k < MLP_B; k++) {
        const __half2* uh = (const __half2*)ua[k];
        const __half2* vh = (const __half2*)va[k];
        const __half2 z2 = __floats2half2_rn(0.f, 0.f);
        __half2 acc0 = z2, acc1 = z2, acc2 = z2, acc3 = z2;
#pragma unroll
        for (int q = 0; q < 16; q += 4) {
            acc0 = __hfma2(h2_relu(__hadd2(uh[q + 0], vh[q + 0])), wl[q + 0], acc0);
            acc1 = __hfma2(h2_relu(__hadd2(uh[q + 1], vh[q + 1])), wl[q + 1], acc1);
            acc2 = __hfma2(h2_relu(__hadd2(uh[q + 2], vh[q + 2])), wl[q + 2], acc2);
            acc3 = __hfma2(h2_relu(__hadd2(uh[q + 3], vh[q + 3])), wl[q + 3], acc3);
        }
        float2 f0 = __half22float2(acc0);
        float2 f1 = __half22float2(acc1);
        float2 f2 = __half22float2(acc2);
        float2 f3 = __half22float2(acc3);
        float acc = b2[0] + (f0.x + f0.y) + (f1.x + f1.y) + (f2.x + f2.y) + (f3.x + f3.y);
        out[t + k * MLP_T] = acc * INV_TEMP;
    }
}

// ---------------------------------------------------------------------------
extern "C" void kernel_launch(void* const* d_in, const int* in_sizes, int n_in,
                              void* d_out, int out_size, void* d_ws, size_t ws_size,
                              hipStream_t stream) {
    const float* x       = (const float*)d_in[0];
    const int*   eidx    = (const int*)d_in[1];          // [2,E] int32
    const float* W       = (const float*)d_in[2];
    const float* att_src = (const float*)d_in[3];
    const float* att_dst = (const float*)d_in[4];
    const float* bias    = (const float*)d_in[5];
    const float* w1      = (const float*)d_in[6];
    const float* b1      = (const float*)d_in[7];
    const float* w2      = (const float*)d_in[8];
    const float* b2      = (const float*)d_in[9];
    float* out = (float*)d_out;

    const int* src = eidx;             // row 0
    const int* dst = eidx + E_EDGES;   // row 1

    // Workspace layout (~50 MB; 16B alignment holds at each boundary).
    int* gcur     = (int*)d_ws;                      // 1568 (zeroed in k_node)
    __half2* w2h  = (__half2*)(gcur + NBKT);         // 16 half2 (64 B)
    int2* recs_g  = (int2*)(w2h + 16);               // NBKT*REG_B recs (22.5 MB)
    float* a_src  = (float*)(recs_g + (size_t)NBKT * REG_B);  // 2N
    float* a_dst  = a_src + 2 * N_NODES;             // 2N
    __half2* xp2  = (__half2*)(a_dst + 2 * N_NODES); // 32N half2 (12.8 MB)
    __half* u     = (__half*)(xp2 + 32 * (size_t)N_NODES);  // 32N halves (6.4 MB)
    __half* v     = u + 32 * (size_t)N_NODES;               // 32N halves (6.4 MB)

    constexpr int BS = 256;

    // K1: node transform (+ gcur zero + w2 pack, fused)
    k_node<<<(N_NODES + BS - 1) / BS, BS, 0, stream>>>(x, W, att_src, att_dst,
                                                      xp2, a_src, a_dst, gcur, w2, w2h);

    // K2: per-(partition,tile) two-pass LDS counting sort -> bucketed records
    k_split<<<NPART * NTH, BS, 0, stream>>>(src, dst, a_src, a_dst, gcur, recs_g);

    // K3: per-bucket LDS sort + aggregation + fused MLP factorization
    k_aggsort<<<NBKT, BS, 0, stream>>>(recs_g, gcur, a_src, a_dst, xp2,
                                       bias, w1, b1, u, v);

    // K4: per-edge logits (edge order, 2 edges/thread)
    k_mlp<<<(MLP_T + BS - 1) / BS, BS, 0, stream>>>(src, dst, (const __half2*)u,
                                                   (const __half2*)v, w2h, b2, out);
}